// Round 3
// baseline (679.544 us; speedup 1.0000x reference)
//
#include <hip/hip_runtime.h>

typedef unsigned short u16;
typedef float floatx4 __attribute__((ext_vector_type(4)));
typedef short shortx8 __attribute__((ext_vector_type(8)));

#define MFMA16(a, b, c) __builtin_amdgcn_mfma_f32_16x16x32_bf16(a, b, c, 0, 0, 0)

__device__ __forceinline__ u16 f2b(float f) {
    union { float f; unsigned u; } c;
    c.f = f;
    unsigned lsb = (c.u >> 16) & 1u;
    c.u += 0x7fffu + lsb;           // round-to-nearest-even
    return (u16)(c.u >> 16);
}

__device__ __forceinline__ shortx8 pack8(float4 a, float4 b) {
    shortx8 r;
    r[0] = (short)f2b(a.x); r[1] = (short)f2b(a.y);
    r[2] = (short)f2b(a.z); r[3] = (short)f2b(a.w);
    r[4] = (short)f2b(b.x); r[5] = (short)f2b(b.y);
    r[6] = (short)f2b(b.z); r[7] = (short)f2b(b.w);
    return r;
}

__global__ __launch_bounds__(256) void scatter_flags(const int* __restrict__ e,
                                                     unsigned char* __restrict__ fl,
                                                     int n) {
    int i = blockIdx.x * 256 + threadIdx.x;
    if (i < n) fl[e[i]] = 1;
}

// Convert weights fp32 [K][N] -> bf16 transposed [N][K] (B-fragment friendly).
__global__ __launch_bounds__(256) void prep_weights(
    const float* __restrict__ W1r, const float* __restrict__ W1o,
    const float* __restrict__ W2r, const float* __restrict__ W2o,
    u16* __restrict__ W1rt, u16* __restrict__ W1ot,
    u16* __restrict__ W2rt, u16* __restrict__ W2ot)
{
    int t = blockIdx.x * 256 + threadIdx.x;
    union { u16 h[4]; unsigned long long ll; } pk;
    if (t < 2048) {                       // W1r: [64][128] -> [128][64]
        int n = t >> 4, k0 = (t & 15) * 4;
        #pragma unroll
        for (int j = 0; j < 4; ++j) pk.h[j] = f2b(W1r[(k0 + j) * 128 + n]);
        *(unsigned long long*)(W1rt + n * 64 + k0) = pk.ll;
    } else if (t < 4096) {                // W1o
        int tt = t - 2048; int n = tt >> 4, k0 = (tt & 15) * 4;
        #pragma unroll
        for (int j = 0; j < 4; ++j) pk.h[j] = f2b(W1o[(k0 + j) * 128 + n]);
        *(unsigned long long*)(W1ot + n * 64 + k0) = pk.ll;
    } else if (t < 8192) {                // W2r: [128][128] -> [128][128]
        int tt = t - 4096; int n = tt >> 5, k0 = (tt & 31) * 4;
        #pragma unroll
        for (int j = 0; j < 4; ++j) pk.h[j] = f2b(W2r[(k0 + j) * 128 + n]);
        *(unsigned long long*)(W2rt + n * 128 + k0) = pk.ll;
    } else if (t < 12288) {               // W2o
        int tt = t - 8192; int n = tt >> 5, k0 = (tt & 31) * 4;
        #pragma unroll
        for (int j = 0; j < 4; ++j) pk.h[j] = f2b(W2o[(k0 + j) * 128 + n]);
        *(unsigned long long*)(W2ot + n * 128 + k0) = pk.ll;
    }
}

// BARRIER-FREE: one wave = one graph (16 nodes x all 128 cols). 4 waves/block,
// each with a private [16][136] bf16 LDS slice for h (same-wave RAW only, no
// __syncthreads anywhere). wbar computed per-lane from uint4 flag loads +
// 2-step shfl_xor degree reduction. Transposed dataflow identical to round-2
// (verified): y1 C-layout == zero-padded-K16 A-frag; MFMA(B,A) = (A.B)^T.
// LDS = 17408 B -> 6+ blocks/CU; launch_bounds(256,6) caps VGPR at ~85.
__global__ __launch_bounds__(256, 6) void sage_mfma(
    const float* __restrict__ x,               // [B*16, 64] f32
    const unsigned char* __restrict__ flags,   // [B*16]
    const float* __restrict__ adjp,            // [16,16] f32
    const float* __restrict__ br1,             // [128] f32
    const float* __restrict__ br2,             // [128] f32
    const u16* __restrict__ W1rt,              // [128][64] bf16 (transposed)
    const u16* __restrict__ W1ot,              // [128][64]
    const u16* __restrict__ W2rt,              // [128][128]
    const u16* __restrict__ W2ot,              // [128][128]
    float* __restrict__ out)                   // [B*16,128] f32
{
    __shared__ __align__(16) u16 smem[4 * 2176];    // 4 waves x [16][136] bf16

    const int tid = threadIdx.x;
    const int w   = tid >> 6;
    const int l   = tid & 63;
    const int q   = l >> 4;
    const int lr  = l & 15;
    const int gg  = blockIdx.x * 4 + w;             // graph index
    u16* hrow = smem + w * 2176;
    const floatx4 fz = {0.f, 0.f, 0.f, 0.f};

    // ---- issue x loads early (A-fragment direct: row lr, k = ks*32+q*8+j) --
    const float* xrow = x + ((size_t)gg * 16 + lr) * 64 + q * 8;
    float4 xv0 = *(const float4*)(xrow);
    float4 xv1 = *(const float4*)(xrow + 4);
    float4 xv2 = *(const float4*)(xrow + 32);
    float4 xv3 = *(const float4*)(xrow + 36);

    // ---- flags (16 bytes, one uint4) + adj row slice ------------------------
    const uint4  flv = *(const uint4*)(flags + (size_t)gg * 16);
    const float4 av  = *(const float4*)(adjp + lr * 16 + q * 4);  // adj[lr][q*4+jj]

    // f_j for j = q*4+jj (select own q's word, extract bytes)
    unsigned wq = (q == 0) ? flv.x : (q == 1) ? flv.y : (q == 2) ? flv.z : flv.w;
    float fj0 = (float)((wq      ) & 1u);
    float fj1 = (float)((wq >>  8) & 1u);
    float fj2 = (float)((wq >> 16) & 1u);
    float fj3 = (float)((wq >> 24) & 1u);
    // deg_i for i = lr: partial over own 4 cols, then sum across the 4 q-groups
    float p = av.x * fj0 + av.y * fj1 + av.z * fj2 + av.w * fj3;
    p += __shfl_xor(p, 16);
    p += __shfl_xor(p, 32);
    // f_i = flag[lr]
    int lw = lr >> 2;
    unsigned wl = (lw == 0) ? flv.x : (lw == 1) ? flv.y : (lw == 2) ? flv.z : flv.w;
    float fi = (float)((wl >> ((lr & 3) * 8)) & 1u);
    float ti = fi / fmaxf(p * fi, 1.0f);            // flag_i / max(deg_i, 1)
    // wbar^T fragment, zero-padded-K16 B layout: elem jj = wbar[i=lr][j=q*4+jj]
    shortx8 wb8 = {0, 0, 0, 0, 0, 0, 0, 0};
    wb8[0] = (short)f2b(ti * fj0 * av.x);
    wb8[1] = (short)f2b(ti * fj1 * av.y);
    wb8[2] = (short)f2b(ti * fj2 * av.z);
    wb8[3] = (short)f2b(ti * fj3 * av.w);

    // ---- x -> bf16 A-frags --------------------------------------------------
    shortx8 ax[2];
    ax[0] = pack8(xv0, xv1);
    ax[1] = pack8(xv2, xv3);

    // ---- layer 1: h = relu(wbar@(x@W1r) + x@W1o + b1), 8 n-tiles ------------
    #pragma unroll
    for (int tni = 0; tni < 8; ++tni) {
        const u16* w1p = W1rt + (tni * 16 + lr) * 64 + q * 8;
        const u16* w1q = W1ot + (tni * 16 + lr) * 64 + q * 8;
        shortx8 b1r0 = *(const shortx8*)(w1p);
        shortx8 b1r1 = *(const shortx8*)(w1p + 32);
        shortx8 b1o0 = *(const shortx8*)(w1q);
        shortx8 b1o1 = *(const shortx8*)(w1q + 32);
        floatx4 bias1 = *(const floatx4*)(br1 + tni * 16 + q * 4);
        floatx4 y1 = MFMA16(ax[0], b1r0, fz);
        y1 = MFMA16(ax[1], b1r1, y1);               // [node][f]
        floatx4 y2t = MFMA16(b1o0, ax[0], bias1);
        y2t = MFMA16(b1o1, ax[1], y2t);             // [f][node] (+bias)
        shortx8 a1 = {(short)f2b(y1[0]), (short)f2b(y1[1]),
                      (short)f2b(y1[2]), (short)f2b(y1[3]), 0, 0, 0, 0};
        floatx4 ag = MFMA16(a1, wb8, y2t);          // agg^T + y2^T + b1
        union { u16 h[4]; unsigned long long ll; } pk;
        #pragma unroll
        for (int r = 0; r < 4; ++r) pk.h[r] = f2b(fmaxf(ag[r], 0.f));
        // lane holds h[node=lr][f = tni*16+q*4+{0..3}] -> row-major private LDS
        *(unsigned long long*)(hrow + lr * 136 + tni * 16 + q * 4) = pk.ll;
    }

    // ---- read back h A-frags (same-wave RAW; lgkmcnt only, no barrier) ------
    shortx8 ah[4];
    #pragma unroll
    for (int ks = 0; ks < 4; ++ks)
        ah[ks] = *(const shortx8*)(hrow + lr * 136 + ks * 32 + q * 8);

    // ---- layer 2: out = wbar@(h@W2r) + h@W2o + b2, 8 n-tiles ----------------
    #pragma unroll
    for (int tni = 0; tni < 8; ++tni) {
        const u16* w2p = W2rt + (tni * 16 + lr) * 128 + q * 8;
        const u16* w2q = W2ot + (tni * 16 + lr) * 128 + q * 8;
        floatx4 u1 = fz;
        floatx4 u2t = *(const floatx4*)(br2 + tni * 16 + q * 4);
        #pragma unroll
        for (int ks = 0; ks < 4; ++ks) {
            shortx8 br_ = *(const shortx8*)(w2p + ks * 32);
            shortx8 bo_ = *(const shortx8*)(w2q + ks * 32);
            u1  = MFMA16(ah[ks], br_, u1);          // [node][fo]
            u2t = MFMA16(bo_, ah[ks], u2t);         // [fo][node] (+bias)
        }
        shortx8 a2 = {(short)f2b(u1[0]), (short)f2b(u1[1]),
                      (short)f2b(u1[2]), (short)f2b(u1[3]), 0, 0, 0, 0};
        floatx4 og = MFMA16(a2, wb8, u2t);          // final tile, transposed
        *(floatx4*)(out + ((size_t)gg * 16 + lr) * 128 + tni * 16 + q * 4) = og;
    }
}

extern "C" void kernel_launch(void* const* d_in, const int* in_sizes, int n_in,
                              void* d_out, int out_size, void* d_ws, size_t ws_size,
                              hipStream_t stream) {
    const float* x    = (const float*)d_in[0];
    const int*   edge = (const int*)d_in[1];
    const float* adjp = (const float*)d_in[2];
    const float* W1r  = (const float*)d_in[3];
    const float* br1  = (const float*)d_in[4];
    const float* W1o  = (const float*)d_in[5];
    const float* W2r  = (const float*)d_in[6];
    const float* br2  = (const float*)d_in[7];
    const float* W2o  = (const float*)d_in[8];
    float* out = (float*)d_out;

    const int total_nodes = in_sizes[0] / 64;      // 524288
    const int nedge       = in_sizes[1];           // 262144
    const int nblocks     = total_nodes / 64;      // 8192 (4 graphs per block)

    unsigned char* flags = (unsigned char*)d_ws;
    u16* wbase = (u16*)((char*)d_ws + 524288);
    u16* W1rt = wbase;            // 8192 u16
    u16* W1ot = wbase + 8192;
    u16* W2rt = wbase + 16384;    // 16384 u16
    u16* W2ot = wbase + 32768;

    hipMemsetAsync(flags, 0, (size_t)total_nodes, stream);
    scatter_flags<<<(nedge + 255) / 256, 256, 0, stream>>>(edge, flags, nedge);
    prep_weights<<<48, 256, 0, stream>>>(W1r, W1o, W2r, W2o, W1rt, W1ot, W2rt, W2ot);
    sage_mfma<<<nblocks, 256, 0, stream>>>(x, flags, adjp, br1, br2,
                                           W1rt, W1ot, W2rt, W2ot, out);
}

// Round 4
// 446.408 us; speedup vs baseline: 1.5222x; 1.5222x over previous
//
#include <hip/hip_runtime.h>

typedef unsigned short u16;
typedef float floatx4 __attribute__((ext_vector_type(4)));
typedef short shortx8 __attribute__((ext_vector_type(8)));

#define MFMA16(a, b, c) __builtin_amdgcn_mfma_f32_16x16x32_bf16(a, b, c, 0, 0, 0)

__device__ __forceinline__ u16 f2b(float f) {
    union { float f; unsigned u; } c;
    c.f = f;
    unsigned lsb = (c.u >> 16) & 1u;
    c.u += 0x7fffu + lsb;           // round-to-nearest-even
    return (u16)(c.u >> 16);
}

__global__ __launch_bounds__(256) void scatter_flags(const int* __restrict__ e,
                                                     unsigned char* __restrict__ fl,
                                                     int n) {
    int i = blockIdx.x * 256 + threadIdx.x;
    if (i < n) fl[e[i]] = 1;
}

// Convert weights fp32 [K][N] -> bf16 transposed [N][K] (B-fragment friendly).
__global__ __launch_bounds__(256) void prep_weights(
    const float* __restrict__ W1r, const float* __restrict__ W1o,
    const float* __restrict__ W2r, const float* __restrict__ W2o,
    u16* __restrict__ W1rt, u16* __restrict__ W1ot,
    u16* __restrict__ W2rt, u16* __restrict__ W2ot)
{
    int t = blockIdx.x * 256 + threadIdx.x;
    union { u16 h[4]; unsigned long long ll; } pk;
    if (t < 2048) {                       // W1r: [64][128] -> [128][64]
        int n = t >> 4, k0 = (t & 15) * 4;
        #pragma unroll
        for (int j = 0; j < 4; ++j) pk.h[j] = f2b(W1r[(k0 + j) * 128 + n]);
        *(unsigned long long*)(W1rt + n * 64 + k0) = pk.ll;
    } else if (t < 4096) {                // W1o
        int tt = t - 2048; int n = tt >> 4, k0 = (tt & 15) * 4;
        #pragma unroll
        for (int j = 0; j < 4; ++j) pk.h[j] = f2b(W1o[(k0 + j) * 128 + n]);
        *(unsigned long long*)(W1ot + n * 64 + k0) = pk.ll;
    } else if (t < 8192) {                // W2r: [128][128] -> [128][128]
        int tt = t - 4096; int n = tt >> 5, k0 = (tt & 31) * 4;
        #pragma unroll
        for (int j = 0; j < 4; ++j) pk.h[j] = f2b(W2r[(k0 + j) * 128 + n]);
        *(unsigned long long*)(W2rt + n * 128 + k0) = pk.ll;
    } else if (t < 12288) {               // W2o
        int tt = t - 8192; int n = tt >> 5, k0 = (tt & 31) * 4;
        #pragma unroll
        for (int j = 0; j < 4; ++j) pk.h[j] = f2b(W2o[(k0 + j) * 128 + n]);
        *(unsigned long long*)(W2ot + n * 128 + k0) = pk.ll;
    }
}

// One block = 4 graphs (64 rows), 4 waves. Wave w owns output cols [2w*16, (2w+2)*16).
// Round-2 verified dataflow; two targeted changes:
//  (1) wbar computed entirely in registers (uint4 flag loads + float4 adjp loads +
//      2-step shfl_xor degree reduction) -- removes the 8-way-bank-conflicted
//      scalar ds_read loop that was serializing the LDS pipe (8M conflict cycles).
//  (2) phase-D output tiles buffered in ogbuf[2][4] and stored tm-ordered so both
//      64-B halves of each 128-B L2 line are written back-to-back (kills the
//      partial-line eviction RMW: WRITE 324->268 MB, FETCH 83->67 MB).
// 2 barriers; LDS = 26624 B.
__global__ __launch_bounds__(256, 4) void sage_mfma(
    const float* __restrict__ x,               // [B*16, 64] f32
    const unsigned char* __restrict__ flags,   // [B*16]
    const float* __restrict__ adjp,            // [16,16] f32
    const float* __restrict__ br1,             // [128] f32
    const float* __restrict__ br2,             // [128] f32
    const u16* __restrict__ W1rt,              // [128][64] bf16 (transposed)
    const u16* __restrict__ W1ot,              // [128][64]
    const u16* __restrict__ W2rt,              // [128][128]
    const u16* __restrict__ W2ot,              // [128][128]
    float* __restrict__ out)                   // [B*16,128] f32
{
    __shared__ __align__(16) unsigned char smem[26624];
    u16* s_x = (u16*)smem;                  // [64][72] bf16 padded (9216 B)
    u16* s_h = (u16*)(smem + 9216);         // [64][136] bf16 padded (17408 B)

    const int b   = blockIdx.x;
    const int tid = threadIdx.x;
    const int w   = tid >> 6;
    const int l   = tid & 63;
    const int q   = l >> 4;
    const int lr  = l & 15;
    const int tn0 = 2 * w;
    const floatx4 fz = {0.f, 0.f, 0.f, 0.f};

    // ---- issue flag/adj loads early (register wbar inputs) ------------------
    uint4 flv[4];
    #pragma unroll
    for (int g = 0; g < 4; ++g)
        flv[g] = *(const uint4*)(flags + (size_t)b * 64 + g * 16);
    const float4 av = *(const float4*)(adjp + lr * 16 + q * 4);  // adj[lr][q*4+jj]

    // ---- stage x (f32 -> bf16, padded rows) ---------------------------------
    {
        const float4* xg = (const float4*)(x + (size_t)b * 4096);
        #pragma unroll
        for (int i = 0; i < 4; ++i) {
            int e = tid + i * 256;
            float4 v = xg[e];
            int row = e >> 4, f = (e & 15) * 4;
            union { u16 h[4]; unsigned long long ll; } pk;
            pk.h[0] = f2b(v.x); pk.h[1] = f2b(v.y); pk.h[2] = f2b(v.z); pk.h[3] = f2b(v.w);
            *(unsigned long long*)(s_x + row * 72 + f) = pk.ll;
        }
    }

    // ---- wbar^T fragments in registers (round-3 verified math, per graph) ---
    // lane(q,lr) elem jj<4 = wbar[i=lr][j=q*4+jj]; elems 4..7 = 0.
    shortx8 wb8[4];
    #pragma unroll
    for (int g = 0; g < 4; ++g) {
        unsigned wq = (q == 0) ? flv[g].x : (q == 1) ? flv[g].y
                    : (q == 2) ? flv[g].z : flv[g].w;
        float fj0 = (float)((wq      ) & 1u);
        float fj1 = (float)((wq >>  8) & 1u);
        float fj2 = (float)((wq >> 16) & 1u);
        float fj3 = (float)((wq >> 24) & 1u);
        float p = av.x * fj0 + av.y * fj1 + av.z * fj2 + av.w * fj3;
        p += __shfl_xor(p, 16);
        p += __shfl_xor(p, 32);                     // deg_i partial-sum across q
        int lw = lr >> 2;
        unsigned wl = (lw == 0) ? flv[g].x : (lw == 1) ? flv[g].y
                    : (lw == 2) ? flv[g].z : flv[g].w;
        float fi = (float)((wl >> ((lr & 3) * 8)) & 1u);
        float ti = fi / fmaxf(p * fi, 1.0f);        // flag_i / max(deg_i, 1)
        shortx8 t = {0, 0, 0, 0, 0, 0, 0, 0};
        t[0] = (short)f2b(ti * fj0 * av.x);
        t[1] = (short)f2b(ti * fj1 * av.y);
        t[2] = (short)f2b(ti * fj2 * av.z);
        t[3] = (short)f2b(ti * fj3 * av.w);
        wb8[g] = t;
    }

    // ---- layer-1 weight fragments + biases (L2-hot) -------------------------
    shortx8 b1r[2][2], b1o[2][2];
    floatx4 bias1[2], bias2[2];
    #pragma unroll
    for (int tni = 0; tni < 2; ++tni) {
        int n0 = (tn0 + tni) * 16;
        bias1[tni] = *(const floatx4*)(br1 + n0 + q * 4);
        bias2[tni] = *(const floatx4*)(br2 + n0 + q * 4);
        int n = n0 + lr;
        #pragma unroll
        for (int ks = 0; ks < 2; ++ks) {
            b1r[tni][ks] = *(const shortx8*)(W1rt + n * 64 + ks * 32 + q * 8);
            b1o[tni][ks] = *(const shortx8*)(W1ot + n * 64 + ks * 32 + q * 8);
        }
    }
    __syncthreads();                                        // barrier 1 of 2

    // ---- Phase A+B fused: h^T = relu(wbar@(x@W1r) + x@W1o + b1) -> s_h ------
    #pragma unroll
    for (int tm = 0; tm < 4; ++tm) {
        shortx8 ax[2];
        #pragma unroll
        for (int ks = 0; ks < 2; ++ks)
            ax[ks] = *(const shortx8*)(s_x + (tm * 16 + lr) * 72 + ks * 32 + q * 8);
        #pragma unroll
        for (int tni = 0; tni < 2; ++tni) {
            floatx4 y1 = fz, y2t = bias1[tni];
            #pragma unroll
            for (int ks = 0; ks < 2; ++ks) {
                y1  = MFMA16(ax[ks], b1r[tni][ks], y1);     // [node][f]
                y2t = MFMA16(b1o[tni][ks], ax[ks], y2t);    // [f][node] (+bias)
            }
            shortx8 a1 = {(short)f2b(y1[0]), (short)f2b(y1[1]),
                          (short)f2b(y1[2]), (short)f2b(y1[3]), 0, 0, 0, 0};
            floatx4 ag = MFMA16(a1, wb8[tm], y2t);          // agg^T + y2^T + b1
            union { u16 h[4]; unsigned long long ll; } pk;
            #pragma unroll
            for (int r = 0; r < 4; ++r) pk.h[r] = f2b(fmaxf(ag[r], 0.f));
            *(unsigned long long*)(s_h + (tm * 16 + lr) * 136 +
                                   (tn0 + tni) * 16 + q * 4) = pk.ll;
        }
    }
    __syncthreads();                                        // barrier 2 of 2

    // ---- Phase C+D fused: out = wbar@(h@W2r) + h@W2o + b2 -------------------
    floatx4 ogbuf[2][4];
    #pragma unroll
    for (int tni = 0; tni < 2; ++tni) {
        int n = (tn0 + tni) * 16 + lr;
        shortx8 b2r[4], b2o[4];
        #pragma unroll
        for (int ks = 0; ks < 4; ++ks) {
            b2r[ks] = *(const shortx8*)(W2rt + n * 128 + ks * 32 + q * 8);
            b2o[ks] = *(const shortx8*)(W2ot + n * 128 + ks * 32 + q * 8);
        }
        #pragma unroll
        for (int tm = 0; tm < 4; ++tm) {
            floatx4 u1 = fz, u2t = bias2[tni];
            #pragma unroll
            for (int ks = 0; ks < 4; ++ks) {
                shortx8 ah = *(const shortx8*)(s_h + (tm * 16 + lr) * 136 +
                                               ks * 32 + q * 8);
                u1  = MFMA16(ah, b2r[ks], u1);              // [node][fo]
                u2t = MFMA16(b2o[ks], ah, u2t);             // [fo][node] (+bias)
            }
            shortx8 a2 = {(short)f2b(u1[0]), (short)f2b(u1[1]),
                          (short)f2b(u1[2]), (short)f2b(u1[3]), 0, 0, 0, 0};
            ogbuf[tni][tm] = MFMA16(a2, wb8[tm], u2t);      // final tile, transposed
        }
    }
    // tm-ordered stores: both 64-B halves of each 128-B line back-to-back
    #pragma unroll
    for (int tm = 0; tm < 4; ++tm) {
        float* op = out + ((size_t)b * 64 + tm * 16 + lr) * 128 + tn0 * 16 + q * 4;
        *(floatx4*)(op)      = ogbuf[0][tm];
        *(floatx4*)(op + 16) = ogbuf[1][tm];
    }
}

extern "C" void kernel_launch(void* const* d_in, const int* in_sizes, int n_in,
                              void* d_out, int out_size, void* d_ws, size_t ws_size,
                              hipStream_t stream) {
    const float* x    = (const float*)d_in[0];
    const int*   edge = (const int*)d_in[1];
    const float* adjp = (const float*)d_in[2];
    const float* W1r  = (const float*)d_in[3];
    const float* br1  = (const float*)d_in[4];
    const float* W1o  = (const float*)d_in[5];
    const float* W2r  = (const float*)d_in[6];
    const float* br2  = (const float*)d_in[7];
    const float* W2o  = (const float*)d_in[8];
    float* out = (float*)d_out;

    const int total_nodes = in_sizes[0] / 64;      // 524288
    const int nedge       = in_sizes[1];           // 262144
    const int nblocks     = total_nodes / 64;      // 8192 (4 graphs per block)

    unsigned char* flags = (unsigned char*)d_ws;
    u16* wbase = (u16*)((char*)d_ws + 524288);
    u16* W1rt = wbase;            // 8192 u16
    u16* W1ot = wbase + 8192;
    u16* W2rt = wbase + 16384;    // 16384 u16
    u16* W2ot = wbase + 32768;

    hipMemsetAsync(flags, 0, (size_t)total_nodes, stream);
    scatter_flags<<<(nedge + 255) / 256, 256, 0, stream>>>(edge, flags, nedge);
    prep_weights<<<48, 256, 0, stream>>>(W1r, W1o, W2r, W2o, W1rt, W1ot, W2rt, W2ot);
    sage_mfma<<<nblocks, 256, 0, stream>>>(x, flags, adjp, br1, br2,
                                           W1rt, W1ot, W2rt, W2ot, out);
}